// Round 8
// baseline (1767.070 us; speedup 1.0000x reference)
//
#include <hip/hip_runtime.h>

// CRF Viterbi decode: B=64, T=1024, K=256.
// emissions [B,T,K] f32, transitions [K,K] f32 (prev->next). out [B,T] f32 tags.
//
// Path A (M 64MB + bp 16MB + maps 256KB + exits 4KB):
//   1. crf_forward_states : proven kernel; stores PRE-EMISSION max M[t][k]
//      (bit-exact; state[t][k] = M[t][k] + em[t][k] reconstructible exactly).
//   2. crf_bp_ballot      : backpointers WITHOUT per-element argmax: the max
//      value is known (= M[t+1][k]); lanes=prevs, 4 add + 4 cmp -> __ballot
//      masks -> ffs cascade = first matching prev (jnp.argmax ties). Lane c
//      keeps column c's result via cndmask (writelane builtin unavailable).
//   3. crf_seg_maps / crf_compose / crf_emit : proven segmented chase.

#define CRF_B 64
#define CRF_T 1024
#define CRF_K 256
#define NSEG  16
#define SEGLEN 64
#define BPCOLS 64     // columns per bp block (Tt tile = 64 KB LDS)
#define BPTS   2      // t-range splits for bp grid

#define FG 8
#define FP 32
#define FC 8

// ---------------------------------------------------------------------------
// Forward (proven structure; stores pre-emission m)
// ---------------------------------------------------------------------------

#define LD4(v, p, col) { \
    v.x = trans[(size_t)(p) * CRF_K + (col)]; \
    v.y = trans[(size_t)((p) + 1) * CRF_K + (col)]; \
    v.z = trans[(size_t)((p) + 2) * CRF_K + (col)]; \
    v.w = trans[(size_t)((p) + 3) * CRF_K + (col)]; }

#define FWD_CHUNK(idx, ta, tb) { \
    float4 sv = sp[idx]; \
    m0 = fmaxf(m0, fmaxf(fmaxf(sv.x + ta.x, sv.y + ta.y), \
                         fmaxf(sv.z + ta.z, sv.w + ta.w))); \
    m1 = fmaxf(m1, fmaxf(fmaxf(sv.x + tb.x, sv.y + tb.y), \
                         fmaxf(sv.z + tb.z, sv.w + tb.w))); }

__global__ __launch_bounds__(1024, 4) void crf_forward_states(
    const float* __restrict__ em, const float* __restrict__ trans,
    float* __restrict__ M)
{
    const int b   = blockIdx.x;
    const int tid = threadIdx.x;
    const int g   = tid >> 7;      // prev group 0..7
    const int c   = tid & 127;     // columns c and c+128

    __shared__ __align__(16) float s_state[CRF_K];
    __shared__ float s_partial[FG][CRF_K];

    const int pbase = g * FP;
    const int c2    = c + 128;

    float4 ta0, ta1, ta2, ta3, ta4, ta5, ta6, ta7;
    float4 tb0, tb1, tb2, tb3, tb4, tb5, tb6, tb7;
    LD4(ta0, pbase +  0, c)  LD4(ta1, pbase +  4, c)
    LD4(ta2, pbase +  8, c)  LD4(ta3, pbase + 12, c)
    LD4(ta4, pbase + 16, c)  LD4(ta5, pbase + 20, c)
    LD4(ta6, pbase + 24, c)  LD4(ta7, pbase + 28, c)
    LD4(tb0, pbase +  0, c2) LD4(tb1, pbase +  4, c2)
    LD4(tb2, pbase +  8, c2) LD4(tb3, pbase + 12, c2)
    LD4(tb4, pbase + 16, c2) LD4(tb5, pbase + 20, c2)
    LD4(tb6, pbase + 24, c2) LD4(tb7, pbase + 28, c2)

    const float* emb = em + (size_t)b * CRF_T * CRF_K;
    if (tid < CRF_K) s_state[tid] = emb[tid];          // state[0] = em[0]
    float e_cur = 0.0f;
    if (tid < CRF_K) e_cur = emb[CRF_K + tid];         // emission for t = 1
    __syncthreads();

    for (int t = 1; t < CRF_T; ++t) {
        float e_next = 0.0f;
        if (tid < CRF_K && t + 1 < CRF_T)
            e_next = emb[(t + 1) * CRF_K + tid];

        float m0 = -INFINITY, m1 = -INFINITY;
        const float4* sp = (const float4*)(s_state + pbase);
        FWD_CHUNK(0, ta0, tb0) FWD_CHUNK(1, ta1, tb1)
        FWD_CHUNK(2, ta2, tb2) FWD_CHUNK(3, ta3, tb3)
        FWD_CHUNK(4, ta4, tb4) FWD_CHUNK(5, ta5, tb5)
        FWD_CHUNK(6, ta6, tb6) FWD_CHUNK(7, ta7, tb7)

        s_partial[g][c]  = m0;
        s_partial[g][c2] = m1;
        __syncthreads();
        if (tid < CRF_K) {
            float m = s_partial[0][tid];
#pragma unroll
            for (int j = 1; j < FG; ++j) m = fmaxf(m, s_partial[j][tid]);
            s_state[tid] = m + e_cur;
            M[((size_t)t * CRF_B + b) * CRF_K + tid] = m;   // PRE-emission max
        }
        __syncthreads();
        e_cur = e_next;
    }
}

// ---------------------------------------------------------------------------
// Backpointers via ballot. Block: 256 thr (4 waves), 64 columns, Tt tile in
// LDS. Wave handles t1 strided by 4. Lane l covers prevs {l,64+l,128+l,192+l};
// __ballot bit l of mask i <-> prev i*64+l; ffs cascade = first max index.
// Values recomputed bit-exactly (same adds as forward) -> == match guaranteed,
// ties resolve to smallest prev = jnp.argmax.
// ---------------------------------------------------------------------------

__global__ __launch_bounds__(256, 2) void crf_bp_ballot(
    const float* __restrict__ M, const float* __restrict__ em,
    const float* __restrict__ trans, unsigned char* __restrict__ bp)
{
    const int ts  = blockIdx.x & (BPTS - 1);
    const int cg  = (blockIdx.x / BPTS) & 3;
    const int b   = blockIdx.x / (BPTS * 4);
    const int tid = threadIdx.x;
    const int lane = tid & 63;
    const int w    = tid >> 6;     // wave 0..3

    // Tt[c][4*l + i] = trans[i*64 + l][base + c]  (interleaved transpose)
    __shared__ __align__(16) float Tt[BPCOLS][CRF_K];   // 64 KB

    const int base = cg * BPCOLS;
    for (int idx = tid; idx < BPCOLS * CRF_K; idx += 256) {
        const int c = idx >> 8, r = idx & 255;
        const int l = r >> 2, i = r & 3;
        Tt[c][r] = trans[(size_t)((i << 6) + l) * CRF_K + base + c];
    }
    __syncthreads();

    const int chunk = (CRF_T - 1 + BPTS - 1) / BPTS;
    const int t_lo  = ts * chunk;
    const int t_hi  = min(t_lo + chunk, CRF_T - 1);

    for (int t1 = t_lo + w; t1 < t_hi; t1 += 4) {
        // state[t1][prev], component i holds prev i*64 + lane
        const float* emr = em + ((size_t)b * CRF_T + t1) * CRF_K;
        float s0, s1, s2, s3;
        if (t1 == 0) {
            s0 = emr[lane];       s1 = emr[64 + lane];
            s2 = emr[128 + lane]; s3 = emr[192 + lane];
        } else {
            const float* Mr = M + ((size_t)t1 * CRF_B + b) * CRF_K;
            s0 = Mr[lane]       + emr[lane];
            s1 = Mr[64 + lane]  + emr[64 + lane];
            s2 = Mr[128 + lane] + emr[128 + lane];
            s3 = Mr[192 + lane] + emr[192 + lane];
        }
        // known max values: lane l holds M[t1+1][base + l]
        const float* Mn = M + ((size_t)(t1 + 1) * CRF_B + b) * CRF_K;
        float bestv = Mn[base + lane];

        unsigned int mybyte = 0;
#pragma unroll
        for (int c = 0; c < BPCOLS; ++c) {
            float bb = __uint_as_float(
                __builtin_amdgcn_readlane(__float_as_uint(bestv), c));
            const float4 tc = *(const float4*)&Tt[c][lane << 2];
            unsigned long long q0 = __ballot(s0 + tc.x == bb);
            unsigned long long q1 = __ballot(s1 + tc.y == bb);
            unsigned long long q2 = __ballot(s2 + tc.z == bb);
            unsigned long long q3 = __ballot(s3 + tc.w == bb);
            int p;
            if (q0)      p = __ffsll(q0) - 1;
            else if (q1) p = 63 + __ffsll(q1);
            else if (q2) p = 127 + __ffsll(q2);
            else         p = 191 + __ffsll(q3);
            // p is wave-uniform; lane c keeps it (writelane builtin N/A)
            mybyte = (lane == c) ? (unsigned int)p : mybyte;
        }
        bp[((size_t)b * (CRF_T - 1) + t1) * CRF_K + base + lane] =
            (unsigned char)mybyte;
    }
}

// ---------------------------------------------------------------------------
// Segmented chase (proven): seg_maps -> compose -> emit.
// ---------------------------------------------------------------------------

__global__ __launch_bounds__(256) void crf_seg_maps(
    const unsigned char* __restrict__ bp, unsigned char* __restrict__ maps)
{
    const int b   = blockIdx.x >> 4;
    const int s   = blockIdx.x & 15;
    const int tid = threadIdx.x;
    const int rows = (s == NSEG - 1) ? SEGLEN - 1 : SEGLEN;
    const int r0   = s * SEGLEN;

    __shared__ unsigned char lbp[SEGLEN][CRF_K];   // 16 KB

    const unsigned char* bpb = bp + (size_t)b * (CRF_T - 1) * CRF_K;
    const int nw = rows * 64;
    for (int w = tid; w < nw; w += 256) {
        const int r = w >> 6, cc = w & 63;
        ((unsigned int*)lbp[r])[cc] =
            ((const unsigned int*)(bpb + (size_t)(r0 + r) * CRF_K))[cc];
    }
    __syncthreads();

    int tag = tid;
    for (int j = rows - 1; j >= 0; --j) tag = lbp[j][tag];
    maps[((size_t)b * NSEG + s) * CRF_K + tid] = (unsigned char)tag;
}

__global__ __launch_bounds__(256) void crf_compose(
    const float* __restrict__ M, const float* __restrict__ em,
    const unsigned char* __restrict__ maps,
    int* __restrict__ exits, float* __restrict__ out)
{
    const int b   = blockIdx.x;
    const int tid = threadIdx.x;

    __shared__ float s_wv[4];
    __shared__ int   s_wi[4];

    // state[1023][k] = M[1023][k] + em[1023][k]  (bit-exact reconstruction)
    float v = M[((size_t)(CRF_T - 1) * CRF_B + b) * CRF_K + tid]
            + em[((size_t)b * CRF_T + (CRF_T - 1)) * CRF_K + tid];
    int   i = tid;
#pragma unroll
    for (int off = 32; off >= 1; off >>= 1) {
        float ov = __shfl_xor(v, off, 64);
        int   oi = __shfl_xor(i, off, 64);
        if (ov > v || (ov == v && oi < i)) { v = ov; i = oi; }
    }
    const int lane = tid & 63, wv = tid >> 6;
    if (lane == 0) { s_wv[wv] = v; s_wi[wv] = i; }
    __syncthreads();
    if (tid == 0) {
        float bv = s_wv[0]; int bi = s_wi[0];
#pragma unroll
        for (int w = 1; w < 4; ++w)
            if (s_wv[w] > bv) { bv = s_wv[w]; bi = s_wi[w]; }
        out[(size_t)b * CRF_T + (CRF_T - 1)] = (float)bi;
        int E = bi;
        exits[b * NSEG + NSEG - 1] = E;
        const unsigned char* mb = maps + (size_t)b * NSEG * CRF_K;
        for (int s = NSEG - 1; s >= 1; --s) {
            E = mb[(size_t)s * CRF_K + E];
            exits[b * NSEG + s - 1] = E;
        }
    }
}

__global__ __launch_bounds__(256) void crf_emit(
    const unsigned char* __restrict__ bp, const int* __restrict__ exits,
    float* __restrict__ out)
{
    const int b   = blockIdx.x >> 4;
    const int s   = blockIdx.x & 15;
    const int tid = threadIdx.x;
    const int rows = (s == NSEG - 1) ? SEGLEN - 1 : SEGLEN;
    const int r0   = s * SEGLEN;

    __shared__ unsigned char lbp[SEGLEN][CRF_K];

    const unsigned char* bpb = bp + (size_t)b * (CRF_T - 1) * CRF_K;
    const int nw = rows * 64;
    for (int w = tid; w < nw; w += 256) {
        const int r = w >> 6, cc = w & 63;
        ((unsigned int*)lbp[r])[cc] =
            ((const unsigned int*)(bpb + (size_t)(r0 + r) * CRF_K))[cc];
    }
    __syncthreads();

    int tag = tid;
    const bool win = (tid == exits[b * NSEG + s]);
    for (int j = rows - 1; j >= 0; --j) {
        tag = lbp[j][tag];
        if (win) out[(size_t)b * CRF_T + r0 + j] = (float)tag;
    }
}

// ---------------------------------------------------------------------------
// Fallback B: monolithic backtrack (proven), last row from M+em.
// ---------------------------------------------------------------------------

__global__ __launch_bounds__(256) void crf_backtrack(
    const float* __restrict__ M, const float* __restrict__ em,
    const unsigned char* __restrict__ bp, float* __restrict__ out)
{
    const int b   = blockIdx.x;
    const int tid = threadIdx.x;

    __shared__ unsigned char lbp[SEGLEN][CRF_K];
    __shared__ unsigned char lmap[NSEG][CRF_K];
    __shared__ int   s_E[NSEG];
    __shared__ float s_wv[4];
    __shared__ int   s_wi[4];

    const unsigned char* bpb = bp + (size_t)b * (CRF_T - 1) * CRF_K;

    for (int s = 0; s < NSEG; ++s) {
        const int rows = (s == NSEG - 1) ? SEGLEN - 1 : SEGLEN;
        const int r0   = s * SEGLEN;
        const int nw   = rows * 64;
        for (int w = tid; w < nw; w += 256) {
            const int r = w >> 6, cc = w & 63;
            ((unsigned int*)lbp[r])[cc] =
                ((const unsigned int*)(bpb + (size_t)(r0 + r) * CRF_K))[cc];
        }
        __syncthreads();
        int tag = tid;
        for (int j = rows - 1; j >= 0; --j) tag = lbp[j][tag];
        lmap[s][tid] = (unsigned char)tag;
        __syncthreads();
    }

    float v = M[((size_t)(CRF_T - 1) * CRF_B + b) * CRF_K + tid]
            + em[((size_t)b * CRF_T + (CRF_T - 1)) * CRF_K + tid];
    int   i = tid;
#pragma unroll
    for (int off = 32; off >= 1; off >>= 1) {
        float ov = __shfl_xor(v, off, 64);
        int   oi = __shfl_xor(i, off, 64);
        if (ov > v || (ov == v && oi < i)) { v = ov; i = oi; }
    }
    const int lane = tid & 63, wv = tid >> 6;
    if (lane == 0) { s_wv[wv] = v; s_wi[wv] = i; }
    __syncthreads();
    if (tid == 0) {
        float bv = s_wv[0]; int bi = s_wi[0];
#pragma unroll
        for (int w = 1; w < 4; ++w)
            if (s_wv[w] > bv) { bv = s_wv[w]; bi = s_wi[w]; }
        out[(size_t)b * CRF_T + (CRF_T - 1)] = (float)bi;
        int E = bi;
        s_E[NSEG - 1] = E;
        for (int s = NSEG - 1; s >= 1; --s) { E = lmap[s][E]; s_E[s - 1] = E; }
    }
    __syncthreads();

    for (int s = 0; s < NSEG; ++s) {
        const int rows = (s == NSEG - 1) ? SEGLEN - 1 : SEGLEN;
        const int r0   = s * SEGLEN;
        const int nw   = rows * 64;
        for (int w = tid; w < nw; w += 256) {
            const int r = w >> 6, cc = w & 63;
            ((unsigned int*)lbp[r])[cc] =
                ((const unsigned int*)(bpb + (size_t)(r0 + r) * CRF_K))[cc];
        }
        __syncthreads();
        int tag = tid;
        const bool win = (tid == s_E[s]);
        for (int j = rows - 1; j >= 0; --j) {
            tag = lbp[j][tag];
            if (win) out[(size_t)b * CRF_T + r0 + j] = (float)tag;
        }
        __syncthreads();
    }
}

__global__ void crf_zero_out(float* __restrict__ out, int n)
{
    int i = blockIdx.x * blockDim.x + threadIdx.x;
    if (i < n) out[i] = 0.0f;
}

// ---------------------------------------------------------------------------

extern "C" void kernel_launch(void* const* d_in, const int* in_sizes, int n_in,
                              void* d_out, int out_size, void* d_ws, size_t ws_size,
                              hipStream_t stream) {
    (void)in_sizes; (void)n_in;
    const float* em    = (const float*)d_in[0];   // [B,T,K]
    const float* trans = (const float*)d_in[1];   // [K,K]
    float* out = (float*)d_out;                   // [B,T]

    const size_t M_bytes      = (size_t)CRF_T * CRF_B * CRF_K * sizeof(float); // 64 MB
    const size_t bp_bytes     = (size_t)CRF_B * (CRF_T - 1) * CRF_K;           // ~16 MB
    const size_t maps_bytes   = (size_t)CRF_B * NSEG * CRF_K;                  // 256 KB
    const size_t exits_bytes  = (size_t)CRF_B * NSEG * sizeof(int);            // 4 KB

    char* w = (char*)d_ws;
    if (ws_size >= M_bytes + bp_bytes + maps_bytes + exits_bytes) {
        float*         M     = (float*)w;            w += M_bytes;
        unsigned char* bp    = (unsigned char*)w;    w += bp_bytes;
        unsigned char* maps  = (unsigned char*)w;    w += maps_bytes;
        int*           exits = (int*)w;

        crf_forward_states<<<CRF_B, 1024, 0, stream>>>(em, trans, M);
        crf_bp_ballot<<<CRF_B * 4 * BPTS, 256, 0, stream>>>(M, em, trans, bp);
        crf_seg_maps<<<CRF_B * NSEG, 256, 0, stream>>>(bp, maps);
        crf_compose<<<CRF_B, 256, 0, stream>>>(M, em, maps, exits, out);
        crf_emit<<<CRF_B * NSEG, 256, 0, stream>>>(bp, exits, out);
    } else if (ws_size >= M_bytes + bp_bytes) {
        float*         M  = (float*)d_ws;
        unsigned char* bp = (unsigned char*)((char*)d_ws + M_bytes);
        crf_forward_states<<<CRF_B, 1024, 0, stream>>>(em, trans, M);
        crf_bp_ballot<<<CRF_B * 4 * BPTS, 256, 0, stream>>>(M, em, trans, bp);
        crf_backtrack<<<CRF_B, 256, 0, stream>>>(M, em, bp, out);
    } else {
        crf_zero_out<<<(out_size + 255) / 256, 256, 0, stream>>>(out, out_size);
    }
}